// Round 11
// baseline (181.108 us; speedup 1.0000x reference)
//
#include <hip/hip_runtime.h>
#include <hip/hip_bf16.h>
#include <stdint.h>

#define BATCH 16384
#define D 1024
#define NCLS 1000
#define NPROTO 5000
#define NPROTO_PAD 5120
#define BM 64                 // rows per block (one block per CU)
#define NCH 5                 // N chunks of 1024 cols (16 waves x 64)
#define NKT 32                // K tiles of 32
#define KSTRIDE (320 * 64 * 8)   // pbf elems per kt

typedef float f32x4 __attribute__((ext_vector_type(4)));
typedef __bf16 bf16x8 __attribute__((ext_vector_type(8)));

__device__ __forceinline__ unsigned short f2bf(float x) {
    unsigned u = __float_as_uint(x);
    u += 0x7FFFu + ((u >> 16) & 1u);   // RNE
    return (unsigned short)(u >> 16);
}

// ---------- normalize rows of z and P to bf16 ----------
// zb:  [BATCH][1024] row-major
// pbf: [kt 0..31][grp 0..319][lane 0..63][8]  (lane = (col&15) + 16*lk)
//      -> a wave's B-fragment load is contiguous 1KB
__global__ __launch_bounds__(256) void k_prep(
        const float* __restrict__ z, const float* __restrict__ P,
        unsigned short* __restrict__ zb, unsigned short* __restrict__ pbf) {
    const int b = blockIdx.x;
    const int t = threadIdx.x;
    const int e0 = 4 * t;
    const float* src = nullptr;
    unsigned short* dst;
    if (b < BATCH) {
        src = z + (size_t)b * D;
        dst = zb + (size_t)b * D + e0;
    } else {
        const int r = b - BATCH;
        const int kt = e0 >> 5;
        const int lk = (e0 >> 3) & 3;
        const int ke = e0 & 7;
        dst = pbf + (((size_t)kt * 320 + (r >> 4)) * 64 + (r & 15) + 16 * lk) * 8 + ke;
        if (r < NPROTO) src = P + (size_t)r * D;
    }
    if (src == nullptr) {                 // padded proto row -> zeros
        *(ushort4*)dst = make_ushort4(0, 0, 0, 0);
        return;
    }
    float4 v = ((const float4*)src)[t];
    float ss = v.x * v.x + v.y * v.y + v.z * v.z + v.w * v.w;
    #pragma unroll
    for (int o = 32; o >= 1; o >>= 1) ss += __shfl_xor(ss, o);
    __shared__ float red[4];
    const int wave = t >> 6;
    if ((t & 63) == 0) red[wave] = ss;
    __syncthreads();
    const float s = red[0] + red[1] + red[2] + red[3];
    const float inv = 1.0f / fmaxf(sqrtf(s), 1e-12f);
    ushort4 o4;
    o4.x = f2bf(v.x * inv); o4.y = f2bf(v.y * inv);
    o4.z = f2bf(v.z * inv); o4.w = f2bf(v.w * inv);
    *(ushort4*)dst = o4;
}

#define MM(A, B, C) __builtin_amdgcn_mfma_f32_16x16x32_bf16(A, B, C, 0, 0, 0)

// ---------- persistent-tile GEMM: A resident in LDS, B streamed to regs ----
// 256 blocks x 1024 threads (16 waves = 4/SIMD). Wave tile 64x64 (acc[4][4]).
// Register budget at 4 waves/SIMD is 128/lane: acc 64 + a 16 + b 32 + addr
// -> pos/neg maxes and labels must NOT be loop-carried in regs (R10 spilled).
// They live in LDS, updated once per chunk.
__global__ __launch_bounds__(1024, 4) void k_gemm(
        const unsigned short* __restrict__ zb,
        const unsigned short* __restrict__ pbf,
        const int* __restrict__ y,
        float* __restrict__ out) {
    // A fragment-packed: LA[kt][row-group 0..3][lane][8]
    __shared__ __align__(16) unsigned short LA[NKT][4][64][8];   // 128 KiB
    __shared__ float redP[16][64];                               // 4 KiB
    __shared__ float redN[16][64];                               // 4 KiB

    const int t = threadIdx.x;
    const int w = t >> 6;                // wave 0..15 = N-slice
    const int lane = t & 63;
    const int lm = lane & 15, lk = lane >> 4;
    const int rowbase = blockIdx.x * BM;

    redP[t >> 6][t & 63] = -INFINITY;
    redN[t >> 6][t & 63] = -INFINITY;

    // ---- one-time: stage this block's 64x1024 A tile, fragment-packed ----
    {
        const int ktw = lane >> 1;
        const int lk0 = (lane & 1) * 2;
        #pragma unroll
        for (int j = 0; j < 4; ++j) {
            const int r = w * 4 + j;
            const unsigned short* gp = zb + (size_t)(rowbase + r) * D + lane * 16;
            const bf16x8 v0 = *(const bf16x8*)gp;
            const bf16x8 v1 = *(const bf16x8*)(gp + 8);
            *(bf16x8*)&LA[ktw][r >> 4][(r & 15) + 16 * lk0][0] = v0;
            *(bf16x8*)&LA[ktw][r >> 4][(r & 15) + 16 * (lk0 + 1)][0] = v1;
        }
    }
    __syncthreads();

    // ---- N-chunk sweep: 5 chunks x 1024 cols; wave w owns cols w*64..+64 --
    #pragma unroll 1
    for (int c = 0; c < NCH; ++c) {
        const int grp0 = c * 64 + w * 4;
        const unsigned short* pB = pbf + ((size_t)grp0 * 64 + lane) * 8;

        f32x4 acc[4][4];
        #pragma unroll
        for (int mi = 0; mi < 4; ++mi)
            #pragma unroll
            for (int ni = 0; ni < 4; ++ni) {
                f32x4 z4 = {0.0f, 0.0f, 0.0f, 0.0f};
                acc[mi][ni] = z4;
            }

        #pragma unroll 1
        for (int kt = 0; kt < NKT; ++kt) {
            // B loads first (global, ~long latency), then LDS a-frags:
            // both in flight together; 16 waves/CU cover the residual.
            const unsigned short* q = pB + (size_t)kt * KSTRIDE;
            const bf16x8 b0 = *(const bf16x8*)(q);
            const bf16x8 b1 = *(const bf16x8*)(q + 512);
            const bf16x8 b2 = *(const bf16x8*)(q + 1024);
            const bf16x8 b3 = *(const bf16x8*)(q + 1536);
            const bf16x8 a0 = *(const bf16x8*)&LA[kt][0][lane][0];
            const bf16x8 a1 = *(const bf16x8*)&LA[kt][1][lane][0];
            const bf16x8 a2 = *(const bf16x8*)&LA[kt][2][lane][0];
            const bf16x8 a3 = *(const bf16x8*)&LA[kt][3][lane][0];
            acc[0][0] = MM(a0, b0, acc[0][0]);
            acc[0][1] = MM(a0, b1, acc[0][1]);
            acc[0][2] = MM(a0, b2, acc[0][2]);
            acc[0][3] = MM(a0, b3, acc[0][3]);
            acc[1][0] = MM(a1, b0, acc[1][0]);
            acc[1][1] = MM(a1, b1, acc[1][1]);
            acc[1][2] = MM(a1, b2, acc[1][2]);
            acc[1][3] = MM(a1, b3, acc[1][3]);
            acc[2][0] = MM(a2, b0, acc[2][0]);
            acc[2][1] = MM(a2, b1, acc[2][1]);
            acc[2][2] = MM(a2, b2, acc[2][2]);
            acc[2][3] = MM(a2, b3, acc[2][3]);
            acc[3][0] = MM(a3, b0, acc[3][0]);
            acc[3][1] = MM(a3, b1, acc[3][1]);
            acc[3][2] = MM(a3, b2, acc[3][2]);
            acc[3][3] = MM(a3, b3, acc[3][3]);
        }

        // merge chunk into LDS-held pos/neg maxes (scalar transients only)
        #pragma unroll
        for (int mi = 0; mi < 4; ++mi) {
            #pragma unroll
            for (int r = 0; r < 4; ++r) {
                const int row = mi * 16 + lk * 4 + r;
                const unsigned yv = (unsigned)y[rowbase + row];
                float pm = -INFINITY, nm = -INFINITY;
                #pragma unroll
                for (int ni = 0; ni < 4; ++ni) {
                    const unsigned col = (unsigned)(c * 1024 + w * 64 + ni * 16 + lm);
                    const unsigned lbl = __umulhi(col, 0xCCCCCCCDu) >> 2; // col/5
                    const float v = acc[mi][ni][r];
                    const bool same = (lbl == yv);
                    pm = same ? fmaxf(pm, v) : pm;
                    nm = (!same && col < NPROTO) ? fmaxf(nm, v) : nm;
                }
                #pragma unroll
                for (int off = 1; off < 16; off <<= 1) {
                    pm = fmaxf(pm, __shfl_xor(pm, off));
                    nm = fmaxf(nm, __shfl_xor(nm, off));
                }
                if (lm == 0) {   // lanes 0,16,32,48 -> distinct rows, same wave
                    redP[w][row] = fmaxf(redP[w][row], pm);
                    redN[w][row] = fmaxf(redN[w][row], nm);
                }
            }
        }
    }

    __syncthreads();
    // final cross-wave merge + direct output write (no atomics)
    if (t < 64) {
        float p = redP[0][t], n = redN[0][t];
        #pragma unroll
        for (int ww = 1; ww < 16; ++ww) {
            p = fmaxf(p, redP[ww][t]);
            n = fmaxf(n, redN[ww][t]);
        }
        out[rowbase + t] = p;
        out[BATCH + rowbase + t] = n;
    }
}

extern "C" void kernel_launch(void* const* d_in, const int* in_sizes, int n_in,
                              void* d_out, int out_size, void* d_ws, size_t ws_size,
                              hipStream_t stream) {
    const float* z = (const float*)d_in[0];
    const int*   y = (const int*)d_in[1];
    const float* P = (const float*)d_in[2];

    // ws: zb 33.5MB | pbf 10.5MB
    unsigned short* zb = (unsigned short*)d_ws;
    unsigned short* pbf = zb + (size_t)BATCH * D;
    float* out = (float*)d_out;

    k_prep<<<BATCH + NPROTO_PAD, 256, 0, stream>>>(z, P, zb, pbf);
    k_gemm<<<BATCH / BM, 1024, 0, stream>>>(zb, pbf, y, out);
}